// Round 1
// baseline (187.519 us; speedup 1.0000x reference)
//
#include <hip/hip_runtime.h>
#include <math.h>

#define N_NODES 1024
#define N_EDGES 32768
#define FEAT    384
#define HID     64

// ---------------------------------------------------------------------------
// K1: q = X@Wq, k = X@Wk, v = X@Wv.  Block = 192 threads (3 waves: q/k/v),
// 4 rows per block, features row staged in LDS (broadcast reads = free).
// ---------------------------------------------------------------------------
__global__ __launch_bounds__(192) void k_kqv(
        const float* __restrict__ feat,
        const float* __restrict__ Wk, const float* __restrict__ Wq,
        const float* __restrict__ Wv,
        float* __restrict__ q, float* __restrict__ k, float* __restrict__ v) {
    __shared__ float fs[4][FEAT];
    const int tid = threadIdx.x;
    const int row0 = blockIdx.x * 4;
    for (int idx = tid; idx < 4 * FEAT; idx += 192)
        fs[idx / FEAT][idx % FEAT] = feat[row0 * FEAT + idx];
    __syncthreads();

    const int col = tid & 63;
    const int which = tid >> 6;                 // wave-uniform: 0=q, 1=k, 2=v
    const float* W = (which == 0) ? Wq : (which == 1 ? Wk : Wv);
    float a0 = 0.f, a1 = 0.f, a2 = 0.f, a3 = 0.f;
    for (int f = 0; f < FEAT; ++f) {
        float wv = W[f * 64 + col];
        a0 = fmaf(fs[0][f], wv, a0);
        a1 = fmaf(fs[1][f], wv, a1);
        a2 = fmaf(fs[2][f], wv, a2);
        a3 = fmaf(fs[3][f], wv, a3);
    }
    float* out = (which == 0) ? q : (which == 1 ? k : v);
    out[(row0 + 0) * 64 + col] = a0;
    out[(row0 + 1) * 64 + col] = a1;
    out[(row0 + 2) * 64 + col] = a2;
    out[(row0 + 3) * 64 + col] = a3;
}

// ---------------------------------------------------------------------------
// K2: A = 2 * q @ k^T.  64x64 tile/block, 4x4 microtile/thread, padded LDS.
// ---------------------------------------------------------------------------
__global__ __launch_bounds__(256) void k_qkt(
        const float* __restrict__ q, const float* __restrict__ k,
        float* __restrict__ A) {
    __shared__ float qs[64][65];
    __shared__ float kst[64][65];   // kst[kk][col]
    const int tid = threadIdx.x;
    const int rowbase = blockIdx.y * 64, colbase = blockIdx.x * 64;
    for (int idx = tid; idx < 4096; idx += 256) {
        int r = idx >> 6, c = idx & 63;
        qs[r][c] = q[(rowbase + r) * 64 + c];
        kst[c][r] = k[(colbase + r) * 64 + c];
    }
    __syncthreads();
    const int tx = tid & 15, ty = tid >> 4;
    float acc[4][4] = {};
    for (int kk = 0; kk < 64; ++kk) {
        float a0 = qs[ty * 4 + 0][kk], a1 = qs[ty * 4 + 1][kk];
        float a2 = qs[ty * 4 + 2][kk], a3 = qs[ty * 4 + 3][kk];
        float b0 = kst[kk][tx * 4 + 0], b1 = kst[kk][tx * 4 + 1];
        float b2 = kst[kk][tx * 4 + 2], b3 = kst[kk][tx * 4 + 3];
        acc[0][0] = fmaf(a0, b0, acc[0][0]); acc[0][1] = fmaf(a0, b1, acc[0][1]);
        acc[0][2] = fmaf(a0, b2, acc[0][2]); acc[0][3] = fmaf(a0, b3, acc[0][3]);
        acc[1][0] = fmaf(a1, b0, acc[1][0]); acc[1][1] = fmaf(a1, b1, acc[1][1]);
        acc[1][2] = fmaf(a1, b2, acc[1][2]); acc[1][3] = fmaf(a1, b3, acc[1][3]);
        acc[2][0] = fmaf(a2, b0, acc[2][0]); acc[2][1] = fmaf(a2, b1, acc[2][1]);
        acc[2][2] = fmaf(a2, b2, acc[2][2]); acc[2][3] = fmaf(a2, b3, acc[2][3]);
        acc[3][0] = fmaf(a3, b0, acc[3][0]); acc[3][1] = fmaf(a3, b1, acc[3][1]);
        acc[3][2] = fmaf(a3, b2, acc[3][2]); acc[3][3] = fmaf(a3, b3, acc[3][3]);
    }
    for (int i = 0; i < 4; ++i) {
        float4 o = make_float4(2.f * acc[i][0], 2.f * acc[i][1],
                               2.f * acc[i][2], 2.f * acc[i][3]);
        *(float4*)&A[(size_t)(rowbase + ty * 4 + i) * N_NODES + colbase + tx * 4] = o;
    }
}

// ---------------------------------------------------------------------------
// K3: per-edge scatter into A:  A[src,dst] += q[src]·trunc(rk) + k[dst]·trunc(rq)
// One 64-lane wave per edge, lane h handles hidden dim h, shuffle-reduce.
// ---------------------------------------------------------------------------
__global__ __launch_bounds__(256) void k_edgeA(
        const int* __restrict__ ei, const float* __restrict__ eattr,
        const float* __restrict__ Ek, const float* __restrict__ Eq,
        const float* __restrict__ q, const float* __restrict__ k,
        const float* __restrict__ bias, const float* __restrict__ mult,
        float* __restrict__ A) {
    const int e = (blockIdx.x * 256 + threadIdx.x) >> 6;
    const int lane = threadIdx.x & 63;
    const int src = ei[e], dst = ei[N_EDGES + e];
    const float w  = 1.0f / (1.0f + expf(-(eattr[e] - bias[0]) * mult[0]));
    const float w1 = 1.0f - w;
    const float rk = truncf(w * Ek[lane] + w1 * Ek[64 + lane]);
    const float rq = truncf(w * Eq[lane] + w1 * Eq[64 + lane]);
    float c = q[src * 64 + lane] * rk + k[dst * 64 + lane] * rq;
    #pragma unroll
    for (int off = 32; off >= 1; off >>= 1) c += __shfl_xor(c, off, 64);
    if (lane == 0) atomicAdd(&A[(size_t)src * N_NODES + dst], c);
}

// ---------------------------------------------------------------------------
// CSR build: count -> exclusive scan -> fill (edge ids grouped by src).
// ---------------------------------------------------------------------------
__global__ void k_count(const int* __restrict__ ei, int* __restrict__ cnt) {
    int e = blockIdx.x * 256 + threadIdx.x;
    if (e < N_EDGES) atomicAdd(&cnt[ei[e]], 1);
}

__global__ __launch_bounds__(1024) void k_scan(
        const int* __restrict__ cnt, int* __restrict__ offs,
        int* __restrict__ cursor) {
    __shared__ int s[1024];
    int t = threadIdx.x;
    s[t] = cnt[t];
    __syncthreads();
    for (int off = 1; off < 1024; off <<= 1) {
        int val = (t >= off) ? s[t - off] : 0;
        __syncthreads();
        s[t] += val;
        __syncthreads();
    }
    offs[t + 1] = s[t];
    if (t == 0) offs[0] = 0;
    cursor[t] = (t == 0) ? 0 : s[t - 1];
}

__global__ void k_fill(const int* __restrict__ ei, int* __restrict__ cursor,
                       int* __restrict__ eids) {
    int e = blockIdx.x * 256 + threadIdx.x;
    if (e < N_EDGES) {
        int pos = atomicAdd(&cursor[ei[e]], 1);
        eids[pos] = e;
    }
}

// ---------------------------------------------------------------------------
// K4: row softmax of A / sqrt(384), in place.  One block per row, float4.
// ---------------------------------------------------------------------------
__global__ __launch_bounds__(256) void k_softmax(float* __restrict__ A) {
    const int row = blockIdx.x, tid = threadIdx.x;
    float4* Ar = (float4*)(A + (size_t)row * N_NODES);
    float4 x = Ar[tid];
    const float inv_s = 0.05103103630798287f;   // 1/sqrt(384)
    float m = fmaxf(fmaxf(x.x, x.y), fmaxf(x.z, x.w));
    #pragma unroll
    for (int off = 32; off >= 1; off >>= 1) m = fmaxf(m, __shfl_xor(m, off, 64));
    __shared__ float redm[4], reds[4];
    const int wid = tid >> 6, lane = tid & 63;
    if (lane == 0) redm[wid] = m;
    __syncthreads();
    m = fmaxf(fmaxf(redm[0], redm[1]), fmaxf(redm[2], redm[3]));
    float e0 = expf((x.x - m) * inv_s);
    float e1 = expf((x.y - m) * inv_s);
    float e2 = expf((x.z - m) * inv_s);
    float e3 = expf((x.w - m) * inv_s);
    float s = e0 + e1 + e2 + e3;
    #pragma unroll
    for (int off = 32; off >= 1; off >>= 1) s += __shfl_xor(s, off, 64);
    if (lane == 0) reds[wid] = s;
    __syncthreads();
    s = reds[0] + reds[1] + reds[2] + reds[3];
    float rs = 1.0f / s;
    Ar[tid] = make_float4(e0 * rs, e1 * rs, e2 * rs, e3 * rs);
}

// ---------------------------------------------------------------------------
// K5: M = A @ v  (+ per-row edge term from CSR).  Grid = 128 row-tiles x 4
// j-quarters; 8 rows/tile; partial sums atomically added into M (zeroed).
// Edge epilogue handled by j-quarter 0 blocks only.
// ---------------------------------------------------------------------------
__global__ __launch_bounds__(256) void k_av(
        const float* __restrict__ A, const float* __restrict__ v,
        const int* __restrict__ ei, const float* __restrict__ eattr,
        const float* __restrict__ Ev, const float* __restrict__ bias,
        const float* __restrict__ mult,
        const int* __restrict__ offs, const int* __restrict__ eids,
        float* __restrict__ M) {
    __shared__ float As[8][256];
    const int tid = threadIdx.x;
    const int tile = blockIdx.x >> 2, jq = blockIdx.x & 3;
    const int row0 = tile * 8, jbase = jq * 256;
    for (int idx = tid; idx < 2048; idx += 256) {
        int r = idx >> 8, c = idx & 255;
        As[r][c] = A[(size_t)(row0 + r) * N_NODES + jbase + c];
    }
    __syncthreads();
    const int d = tid & 63, g = tid >> 6;       // group g owns rows g*2, g*2+1
    float acc0 = 0.f, acc1 = 0.f;
    for (int j = 0; j < 256; ++j) {
        float vv = v[(jbase + j) * 64 + d];
        acc0 = fmaf(As[g * 2 + 0][j], vv, acc0);
        acc1 = fmaf(As[g * 2 + 1][j], vv, acc1);
    }
    if (jq == 0) {
        const float ev0 = Ev[d], ev1 = Ev[64 + d];
        const float b = bias[0], mu = mult[0];
        for (int rr = 0; rr < 2; ++rr) {
            const int row = row0 + g * 2 + rr;
            const int beg = offs[row], end = offs[row + 1];
            float accE = 0.f;
            for (int p = beg; p < end; ++p) {
                int e = eids[p];
                int dst = ei[N_EDGES + e];
                float w = 1.0f / (1.0f + expf(-(eattr[e] - b) * mu));
                float rv = w * ev0 + (1.0f - w) * ev1;
                accE = fmaf(A[(size_t)row * N_NODES + dst], rv, accE);
            }
            if (rr == 0) acc0 += accE; else acc1 += accE;
        }
    }
    atomicAdd(&M[(row0 + g * 2 + 0) * 64 + d], acc0);
    atomicAdd(&M[(row0 + g * 2 + 1) * 64 + d], acc1);
}

// ---------------------------------------------------------------------------
extern "C" void kernel_launch(void* const* d_in, const int* in_sizes, int n_in,
                              void* d_out, int out_size, void* d_ws, size_t ws_size,
                              hipStream_t stream) {
    (void)in_sizes; (void)n_in; (void)out_size; (void)ws_size;
    const float* feat  = (const float*)d_in[0];
    const int*   ei    = (const int*)d_in[1];
    const float* eattr = (const float*)d_in[2];
    const float* Wk    = (const float*)d_in[3];
    const float* Wq    = (const float*)d_in[4];
    const float* Wv    = (const float*)d_in[5];
    const float* Ek    = (const float*)d_in[6];
    const float* Eq    = (const float*)d_in[7];
    const float* Ev    = (const float*)d_in[8];
    const float* bias  = (const float*)d_in[9];
    const float* mult  = (const float*)d_in[10];
    float* M = (float*)d_out;

    float* wsf = (float*)d_ws;
    float* q = wsf;                     // 1024*64
    float* k = wsf + 65536;             // 1024*64
    float* v = wsf + 131072;            // 1024*64
    float* A = wsf + 196608;            // 1024*1024
    int* ibase  = (int*)(wsf + 196608 + 1048576);
    int* cnt    = ibase;                // 1024
    int* offs   = ibase + 1024;         // 1025
    int* cursor = ibase + 2052;         // 1024
    int* eids   = ibase + 3080;         // 32768

    hipMemsetAsync(cnt, 0, 1024 * sizeof(int), stream);
    hipMemsetAsync(M, 0, (size_t)N_NODES * 64 * sizeof(float), stream);

    k_kqv<<<256, 192, 0, stream>>>(feat, Wk, Wq, Wv, q, k, v);
    k_count<<<128, 256, 0, stream>>>(ei, cnt);
    k_scan<<<1, 1024, 0, stream>>>(cnt, offs, cursor);
    k_fill<<<128, 256, 0, stream>>>(ei, cursor, eids);
    k_qkt<<<dim3(16, 16), 256, 0, stream>>>(q, k, A);
    k_edgeA<<<8192, 256, 0, stream>>>(ei, eattr, Ek, Eq, q, k, bias, mult, A);
    k_softmax<<<N_NODES, 256, 0, stream>>>(A);
    k_av<<<512, 256, 0, stream>>>(A, v, ei, eattr, Ev, bias, mult, offs, eids, M);
}

// Round 2
// 134.011 us; speedup vs baseline: 1.3993x; 1.3993x over previous
//
#include <hip/hip_runtime.h>
#include <math.h>

#define N_NODES 1024
#define N_EDGES 32768
#define FEAT    384

// ---------------------------------------------------------------------------
// K1: q = X@Wq, k = X@Wk, v = X@Wv.  Block = 192 threads (3 waves: q/k/v),
// 4 rows per block, features staged in LDS.  Block 0 also zeroes S[2048].
// ---------------------------------------------------------------------------
__global__ __launch_bounds__(192) void k_kqv(
        const float* __restrict__ feat,
        const float* __restrict__ Wk, const float* __restrict__ Wq,
        const float* __restrict__ Wv,
        float* __restrict__ q, float* __restrict__ k, float* __restrict__ v,
        float* __restrict__ S) {
    __shared__ float fs[4][FEAT];
    const int tid = threadIdx.x;
    const int row0 = blockIdx.x * 4;
    if (blockIdx.x == 0)
        for (int i = tid; i < 2 * N_NODES; i += 192) S[i] = 0.f;
    for (int idx = tid; idx < 4 * FEAT; idx += 192)
        fs[idx / FEAT][idx % FEAT] = feat[row0 * FEAT + idx];
    __syncthreads();

    const int col = tid & 63;
    const int which = tid >> 6;                 // wave-uniform: 0=q, 1=k, 2=v
    const float* W = (which == 0) ? Wq : (which == 1 ? Wk : Wv);
    float a0 = 0.f, a1 = 0.f, a2 = 0.f, a3 = 0.f;
    for (int f = 0; f < FEAT; ++f) {
        float wv = W[f * 64 + col];
        a0 = fmaf(fs[0][f], wv, a0);
        a1 = fmaf(fs[1][f], wv, a1);
        a2 = fmaf(fs[2][f], wv, a2);
        a3 = fmaf(fs[3][f], wv, a3);
    }
    float* out = (which == 0) ? q : (which == 1 ? k : v);
    out[(row0 + 0) * 64 + col] = a0;
    out[(row0 + 1) * 64 + col] = a1;
    out[(row0 + 2) * 64 + col] = a2;
    out[(row0 + 3) * 64 + col] = a3;
}

// ---------------------------------------------------------------------------
// K2: A = 2 * q @ k^T.  64x64 tile/block, 4x4 microtile/thread, padded LDS.
// ---------------------------------------------------------------------------
__global__ __launch_bounds__(256) void k_qkt(
        const float* __restrict__ q, const float* __restrict__ k,
        float* __restrict__ A) {
    __shared__ float qs[64][65];
    __shared__ float kst[64][65];   // kst[kk][col]
    const int tid = threadIdx.x;
    const int rowbase = blockIdx.y * 64, colbase = blockIdx.x * 64;
    for (int idx = tid; idx < 4096; idx += 256) {
        int r = idx >> 6, c = idx & 63;
        qs[r][c] = q[(rowbase + r) * 64 + c];
        kst[c][r] = k[(colbase + r) * 64 + c];
    }
    __syncthreads();
    const int tx = tid & 15, ty = tid >> 4;
    float acc[4][4] = {};
    for (int kk = 0; kk < 64; ++kk) {
        float a0 = qs[ty * 4 + 0][kk], a1 = qs[ty * 4 + 1][kk];
        float a2 = qs[ty * 4 + 2][kk], a3 = qs[ty * 4 + 3][kk];
        float b0 = kst[kk][tx * 4 + 0], b1 = kst[kk][tx * 4 + 1];
        float b2 = kst[kk][tx * 4 + 2], b3 = kst[kk][tx * 4 + 3];
        acc[0][0] = fmaf(a0, b0, acc[0][0]); acc[0][1] = fmaf(a0, b1, acc[0][1]);
        acc[0][2] = fmaf(a0, b2, acc[0][2]); acc[0][3] = fmaf(a0, b3, acc[0][3]);
        acc[1][0] = fmaf(a1, b0, acc[1][0]); acc[1][1] = fmaf(a1, b1, acc[1][1]);
        acc[1][2] = fmaf(a1, b2, acc[1][2]); acc[1][3] = fmaf(a1, b3, acc[1][3]);
        acc[2][0] = fmaf(a2, b0, acc[2][0]); acc[2][1] = fmaf(a2, b1, acc[2][1]);
        acc[2][2] = fmaf(a2, b2, acc[2][2]); acc[2][3] = fmaf(a2, b3, acc[2][3]);
        acc[3][0] = fmaf(a3, b0, acc[3][0]); acc[3][1] = fmaf(a3, b1, acc[3][1]);
        acc[3][2] = fmaf(a3, b2, acc[3][2]); acc[3][3] = fmaf(a3, b3, acc[3][3]);
    }
    for (int i = 0; i < 4; ++i) {
        float4 o = make_float4(2.f * acc[i][0], 2.f * acc[i][1],
                               2.f * acc[i][2], 2.f * acc[i][3]);
        *(float4*)&A[(size_t)(rowbase + ty * 4 + i) * N_NODES + colbase + tx * 4] = o;
    }
}

// ---------------------------------------------------------------------------
// K3: per-edge scatter into A:  A[src,dst] += q[src]·trunc(rk) + k[dst]·trunc(rq)
// One 64-lane wave per edge, lane h handles hidden dim h, shuffle-reduce.
// Also stores the per-edge sigmoid weight w for reuse by k_edgeS.
// ---------------------------------------------------------------------------
__global__ __launch_bounds__(256) void k_edgeA(
        const int* __restrict__ ei, const float* __restrict__ eattr,
        const float* __restrict__ Ek, const float* __restrict__ Eq,
        const float* __restrict__ q, const float* __restrict__ k,
        const float* __restrict__ bias, const float* __restrict__ mult,
        float* __restrict__ A, float* __restrict__ wbuf) {
    const int e = (blockIdx.x * 256 + threadIdx.x) >> 6;
    const int lane = threadIdx.x & 63;
    const int src = ei[e], dst = ei[N_EDGES + e];
    const float w  = 1.0f / (1.0f + expf(-(eattr[e] - bias[0]) * mult[0]));
    const float w1 = 1.0f - w;
    const float rk = truncf(w * Ek[lane] + w1 * Ek[64 + lane]);
    const float rq = truncf(w * Eq[lane] + w1 * Eq[64 + lane]);
    float c = q[src * 64 + lane] * rk + k[dst * 64 + lane] * rq;
    #pragma unroll
    for (int off = 32; off >= 1; off >>= 1) c += __shfl_xor(c, off, 64);
    if (lane == 0) {
        atomicAdd(&A[(size_t)src * N_NODES + dst], c);
        wbuf[e] = w;
    }
}

// ---------------------------------------------------------------------------
// K4: row softmax of A / sqrt(384), in place.  One block per row, float4.
// ---------------------------------------------------------------------------
__global__ __launch_bounds__(256) void k_softmax(float* __restrict__ A) {
    const int row = blockIdx.x, tid = threadIdx.x;
    float4* Ar = (float4*)(A + (size_t)row * N_NODES);
    float4 x = Ar[tid];
    const float inv_s = 0.05103103630798287f;   // 1/sqrt(384)
    float m = fmaxf(fmaxf(x.x, x.y), fmaxf(x.z, x.w));
    #pragma unroll
    for (int off = 32; off >= 1; off >>= 1) m = fmaxf(m, __shfl_xor(m, off, 64));
    __shared__ float redm[4], reds[4];
    const int wid = tid >> 6, lane = tid & 63;
    if (lane == 0) redm[wid] = m;
    __syncthreads();
    m = fmaxf(fmaxf(redm[0], redm[1]), fmaxf(redm[2], redm[3]));
    float e0 = expf((x.x - m) * inv_s);
    float e1 = expf((x.y - m) * inv_s);
    float e2 = expf((x.z - m) * inv_s);
    float e3 = expf((x.w - m) * inv_s);
    float s = e0 + e1 + e2 + e3;
    #pragma unroll
    for (int off = 32; off >= 1; off >>= 1) s += __shfl_xor(s, off, 64);
    if (lane == 0) reds[wid] = s;
    __syncthreads();
    s = reds[0] + reds[1] + reds[2] + reds[3];
    float rs = 1.0f / s;
    Ar[tid] = make_float4(e0 * rs, e1 * rs, e2 * rs, e3 * rs);
}

// ---------------------------------------------------------------------------
// K5: per-edge S accumulation.  S0[row] = sum_e A[row,dst]*w_e,
//     S1[row] = sum_e A[row,dst]*(1-w_e).  S interleaved [row*2 + {0,1}].
// The value-embedding einsum factorizes through these two scalars.
// ---------------------------------------------------------------------------
__global__ __launch_bounds__(256) void k_edgeS(
        const int* __restrict__ ei, const float* __restrict__ wbuf,
        const float* __restrict__ A, float* __restrict__ S) {
    const int e = blockIdx.x * 256 + threadIdx.x;
    const int src = ei[e], dst = ei[N_EDGES + e];
    const float w = wbuf[e];
    const float a = A[(size_t)src * N_NODES + dst];
    atomicAdd(&S[src * 2 + 0], a * w);
    atomicAdd(&S[src * 2 + 1], a * (1.0f - w));
}

// ---------------------------------------------------------------------------
// K6: M = A @ v + S0*Ev0 + S1*Ev1.  256 blocks x 4 rows; A rows staged in
// LDS; j-range split across 4 waves; float4 LDS reads; cross-wave reduce.
// No atomics, direct store.
// ---------------------------------------------------------------------------
__global__ __launch_bounds__(256) void k_av(
        const float* __restrict__ A, const float* __restrict__ v,
        const float* __restrict__ Ev, const float* __restrict__ S,
        float* __restrict__ M) {
    __shared__ float As[4][N_NODES];        // 16 KB
    __shared__ float red[4][4][64];         // [r][wave][d], 4 KB
    const int tid = threadIdx.x;
    const int row0 = blockIdx.x * 4;
    for (int idx = tid; idx < 1024; idx += 256)
        ((float4*)As)[idx] = ((const float4*)(A + (size_t)row0 * N_NODES))[idx];
    __syncthreads();

    const int wave = tid >> 6, d = tid & 63;
    const int jbase = wave * 256;
    float acc0 = 0.f, acc1 = 0.f, acc2 = 0.f, acc3 = 0.f;
    #pragma unroll 4
    for (int j0 = 0; j0 < 256; j0 += 4) {
        const int j = jbase + j0;
        float4 a0 = *(const float4*)&As[0][j];
        float4 a1 = *(const float4*)&As[1][j];
        float4 a2 = *(const float4*)&As[2][j];
        float4 a3 = *(const float4*)&As[3][j];
        float v0 = v[(j + 0) * 64 + d];
        float v1 = v[(j + 1) * 64 + d];
        float v2 = v[(j + 2) * 64 + d];
        float v3 = v[(j + 3) * 64 + d];
        acc0 = fmaf(a0.x, v0, acc0); acc0 = fmaf(a0.y, v1, acc0);
        acc0 = fmaf(a0.z, v2, acc0); acc0 = fmaf(a0.w, v3, acc0);
        acc1 = fmaf(a1.x, v0, acc1); acc1 = fmaf(a1.y, v1, acc1);
        acc1 = fmaf(a1.z, v2, acc1); acc1 = fmaf(a1.w, v3, acc1);
        acc2 = fmaf(a2.x, v0, acc2); acc2 = fmaf(a2.y, v1, acc2);
        acc2 = fmaf(a2.z, v2, acc2); acc2 = fmaf(a2.w, v3, acc2);
        acc3 = fmaf(a3.x, v0, acc3); acc3 = fmaf(a3.y, v1, acc3);
        acc3 = fmaf(a3.z, v2, acc3); acc3 = fmaf(a3.w, v3, acc3);
    }
    red[0][wave][d] = acc0;
    red[1][wave][d] = acc1;
    red[2][wave][d] = acc2;
    red[3][wave][d] = acc3;
    __syncthreads();

    const int r = tid >> 6;                 // reuse: thread -> (row r, dim d)
    const int row = row0 + r;
    float m = red[r][0][d] + red[r][1][d] + red[r][2][d] + red[r][3][d];
    m += S[row * 2 + 0] * Ev[d] + S[row * 2 + 1] * Ev[64 + d];
    M[row * 64 + d] = m;
}

// ---------------------------------------------------------------------------
extern "C" void kernel_launch(void* const* d_in, const int* in_sizes, int n_in,
                              void* d_out, int out_size, void* d_ws, size_t ws_size,
                              hipStream_t stream) {
    (void)in_sizes; (void)n_in; (void)out_size; (void)ws_size;
    const float* feat  = (const float*)d_in[0];
    const int*   ei    = (const int*)d_in[1];
    const float* eattr = (const float*)d_in[2];
    const float* Wk    = (const float*)d_in[3];
    const float* Wq    = (const float*)d_in[4];
    const float* Wv    = (const float*)d_in[5];
    const float* Ek    = (const float*)d_in[6];
    const float* Eq    = (const float*)d_in[7];
    const float* Ev    = (const float*)d_in[8];
    const float* bias  = (const float*)d_in[9];
    const float* mult  = (const float*)d_in[10];
    float* M = (float*)d_out;

    float* wsf = (float*)d_ws;
    float* q    = wsf;                      // 1024*64
    float* k    = wsf + 65536;              // 1024*64
    float* v    = wsf + 131072;             // 1024*64
    float* A    = wsf + 196608;             // 1024*1024
    float* S    = wsf + 196608 + 1048576;   // 2048 (S0/S1 interleaved)
    float* wbuf = S + 2048;                 // 32768 (per-edge sigmoid weight)

    k_kqv<<<256, 192, 0, stream>>>(feat, Wk, Wq, Wv, q, k, v, S);
    k_qkt<<<dim3(16, 16), 256, 0, stream>>>(q, k, A);
    k_edgeA<<<8192, 256, 0, stream>>>(ei, eattr, Ek, Eq, q, k, bias, mult, A, wbuf);
    k_softmax<<<N_NODES, 256, 0, stream>>>(A);
    k_edgeS<<<128, 256, 0, stream>>>(ei, wbuf, A, S);
    k_av<<<256, 256, 0, stream>>>(A, v, Ev, S, M);
}